// Round 1
// baseline (369.729 us; speedup 1.0000x reference)
//
#include <hip/hip_runtime.h>
#include <math.h>

#define EC_N 64

struct __align__(16) NerfParam {
    // q = c00*x*x + c11*y*y + c22*z*z + c01_2*x*y + c02_2*x*z + c12_2*y*z
    float c00, c11, c22, c01_2;
    float c02_2, c12_2, cx, cy;
    float cz, cc, pad0, pad1;
};

__global__ void init_penalty_kernel(const float* __restrict__ centers,
                                    float* __restrict__ pen_out) {
    // one wave (64 threads); each lane does one nerflet's bbox penalty
    int e = threadIdx.x;
    float p = 0.f;
    if (e < EC_N) {
        const float bmax[3] = {0.6f, 0.6f, 0.6f};
        const float bmin[3] = {-0.6f, -0.6f, -0.35f};
        #pragma unroll
        for (int k = 0; k < 3; ++k) {
            float cv = centers[e * 3 + k];
            p += fmaxf(cv - bmax[k], 0.f) + fmaxf(bmin[k] - cv, 0.f);
        }
    }
    #pragma unroll
    for (int off = 32; off > 0; off >>= 1)
        p += __shfl_down(p, off, 64);
    if (threadIdx.x == 0) *pen_out = p;   // overwrites poison; main kernel atomicAdds on top
}

__global__ __launch_bounds__(256) void rbf_main_kernel(
    const float* __restrict__ wsp,        // [N,3]
    const float* __restrict__ act,        // [EC,N,4]
    const float* __restrict__ dists,      // [N,1]
    const float* __restrict__ constants,  // [EC,1]
    const float* __restrict__ centers,    // [EC,3]
    const float* __restrict__ radii,      // [EC,3]
    const float* __restrict__ rotations,  // [EC,3]
    float* __restrict__ out,              // [N,4]
    float* __restrict__ pen,              // scalar (pre-initialized with bbox term)
    int n)
{
    __shared__ NerfParam sp[EC_N];
    __shared__ float s_pen[4];

    const int tid = threadIdx.x;

    // ---- per-block nerflet parameter setup (redundant across blocks, tiny) ----
    if (tid < EC_N) {
        const int e = tid;
        float c = fabsf(constants[e]);
        float r0 = fabsf(radii[e * 3 + 0]) + 0.005f;
        float r1 = fabsf(radii[e * 3 + 1]) + 0.005f;
        float r2 = fabsf(radii[e * 3 + 2]) + 0.005f;
        float d0 = 1.f / (r0 + 1e-8f);
        float d1 = 1.f / (r1 + 1e-8f);
        float d2 = 1.f / (r2 + 1e-8f);
        float ax = rotations[e * 3 + 0];
        float ay = rotations[e * 3 + 1];
        float az = rotations[e * 3 + 2];
        float sx, cx, sy, cy, sz, cz;
        sincosf(ax, &sx, &cx);
        sincosf(ay, &sy, &cy);
        sincosf(az, &sz, &cz);
        float R00 = cz * cy;
        float R01 = cz * sy * sx - sz * cx;
        float R02 = cz * sy * cx + sz * sx;
        float R10 = sz * cy;
        float R11 = sz * sy * sx + cz * cx;
        float R12 = sz * sy * cx - cz * sx;
        float R20 = -sy;
        float R21 = cy * sx;
        float R22 = cy * cx;
        // inv_cov = R diag(d) R^T
        float c00 = R00 * R00 * d0 + R01 * R01 * d1 + R02 * R02 * d2;
        float c11 = R10 * R10 * d0 + R11 * R11 * d1 + R12 * R12 * d2;
        float c22 = R20 * R20 * d0 + R21 * R21 * d1 + R22 * R22 * d2;
        float c01 = R00 * R10 * d0 + R01 * R11 * d1 + R02 * R12 * d2;
        float c02 = R00 * R20 * d0 + R01 * R21 * d1 + R02 * R22 * d2;
        float c12 = R10 * R20 * d0 + R11 * R21 * d1 + R12 * R22 * d2;
        NerfParam p;
        p.c00 = c00; p.c11 = c11; p.c22 = c22;
        p.c01_2 = 2.f * c01; p.c02_2 = 2.f * c02; p.c12_2 = 2.f * c12;
        p.cx = centers[e * 3 + 0];
        p.cy = centers[e * 3 + 1];
        p.cz = centers[e * 3 + 2];
        p.cc = c;
        p.pad0 = 0.f; p.pad1 = 0.f;
        sp[e] = p;
    }
    __syncthreads();

    const int i = blockIdx.x * 256 + tid;
    float penLocal = 0.f;

    if (i < n) {
        const float px = wsp[i * 3 + 0];
        const float py = wsp[i * 3 + 1];
        const float pz = wsp[i * 3 + 2];
        const float dist = dists[i];

        float S = 0.f, v0 = 0.f, v1 = 0.f, v2 = 0.f, v3 = 0.f;

        #pragma unroll 8
        for (int e = 0; e < EC_N; ++e) {
            const NerfParam p = sp[e];
            const float x = px - p.cx;
            const float y = py - p.cy;
            const float z = pz - p.cz;
            float q = x * x * p.c00;
            q = fmaf(y * y, p.c11, q);
            q = fmaf(z * z, p.c22, q);
            q = fmaf(x * y, p.c01_2, q);
            q = fmaf(x * z, p.c02_2, q);
            q = fmaf(y * z, p.c12_2, q);
            const float rbf = __expf(-0.5f * q) * p.cc;
            S += rbf;
            penLocal += fmaxf(rbf - 0.01f, 0.f);

            const float4 a = *(const float4*)(act + ((size_t)e * (size_t)n + (size_t)i) * 4);
            const float s0 = 1.f / (1.f + __expf(-a.x));
            const float s1 = 1.f / (1.f + __expf(-a.y));
            const float s2 = 1.f / (1.f + __expf(-a.z));
            const float al = 1.f - __expf(-fmaxf(a.w, 0.f) * dist);
            v0 = fmaf(rbf, s0, v0);
            v1 = fmaf(rbf, s1, v1);
            v2 = fmaf(rbf, s2, v2);
            v3 = fmaf(rbf, al, v3);
        }

        const float inv = 1.f / (S + 1e-6f);
        float4 o;
        o.x = v0 * inv; o.y = v1 * inv; o.z = v2 * inv; o.w = v3 * inv;
        *(float4*)(out + (size_t)i * 4) = o;
    }

    // ---- penalty reduction: shuffle within wave, LDS across waves, one atomic/block ----
    #pragma unroll
    for (int off = 32; off > 0; off >>= 1)
        penLocal += __shfl_down(penLocal, off, 64);
    const int wave = tid >> 6;
    const int lane = tid & 63;
    if (lane == 0) s_pen[wave] = penLocal;
    __syncthreads();
    if (tid == 0) {
        const float t = s_pen[0] + s_pen[1] + s_pen[2] + s_pen[3];
        atomicAdd(pen, t * (0.001f / (float)n));
    }
}

extern "C" void kernel_launch(void* const* d_in, const int* in_sizes, int n_in,
                              void* d_out, int out_size, void* d_ws, size_t ws_size,
                              hipStream_t stream) {
    const float* wsp       = (const float*)d_in[0];
    const float* act       = (const float*)d_in[1];
    const float* dists     = (const float*)d_in[2];
    const float* constants = (const float*)d_in[3];
    const float* centers   = (const float*)d_in[4];
    const float* radii     = (const float*)d_in[5];
    const float* rotations = (const float*)d_in[6];

    const int n = in_sizes[0] / 3;           // world_space_points is [N,3]
    float* out = (float*)d_out;              // [N,4] flat
    float* pen = out + (size_t)n * 4;        // scalar penalty at the end

    init_penalty_kernel<<<1, 64, 0, stream>>>(centers, pen);

    const int blocks = (n + 255) / 256;
    rbf_main_kernel<<<blocks, 256, 0, stream>>>(
        wsp, act, dists, constants, centers, radii, rotations, out, pen, n);
}

// Round 2
// 360.515 us; speedup vs baseline: 1.0256x; 1.0256x over previous
//
#include <hip/hip_runtime.h>
#include <math.h>

#define EC_N 64
// exp(-0.5*q) == exp2(q * -0.5*log2(e)); fold the scale into the coefficients
#define NEG_HALF_LOG2E (-0.72134752044448170368f)
#define NEG_LOG2E      (-1.44269504088896340736f)

typedef float v4f __attribute__((ext_vector_type(4)));

struct __align__(16) NerfParam {
    // q' = c00*x*x + c11*y*y + c22*z*z + c01_2*x*y + c02_2*x*z + c12_2*y*z
    // coefficients pre-scaled by -0.5*log2(e) so rbf = exp2(q') * cc
    float c00, c11, c22, c01_2;
    float c02_2, c12_2, cx, cy;
    float cz, cc, pad0, pad1;
};

__device__ __forceinline__ float fast_exp2(float x) { return __builtin_amdgcn_exp2f(x); }
__device__ __forceinline__ float fast_rcp(float x)  { return __builtin_amdgcn_rcpf(x); }

__global__ void init_penalty_kernel(const float* __restrict__ centers,
                                    float* __restrict__ pen_out) {
    // one wave (64 threads); each lane does one nerflet's bbox penalty
    int e = threadIdx.x;
    float p = 0.f;
    if (e < EC_N) {
        const float bmax[3] = {0.6f, 0.6f, 0.6f};
        const float bmin[3] = {-0.6f, -0.6f, -0.35f};
        #pragma unroll
        for (int k = 0; k < 3; ++k) {
            float cv = centers[e * 3 + k];
            p += fmaxf(cv - bmax[k], 0.f) + fmaxf(bmin[k] - cv, 0.f);
        }
    }
    #pragma unroll
    for (int off = 32; off > 0; off >>= 1)
        p += __shfl_down(p, off, 64);
    if (threadIdx.x == 0) *pen_out = p;   // overwrites poison; main kernel atomicAdds on top
}

__global__ __launch_bounds__(256, 2) void rbf_main_kernel(
    const float* __restrict__ wsp,        // [N,3]
    const float* __restrict__ act,        // [EC,N,4]
    const float* __restrict__ dists,      // [N,1]
    const float* __restrict__ constants,  // [EC,1]
    const float* __restrict__ centers,    // [EC,3]
    const float* __restrict__ radii,      // [EC,3]
    const float* __restrict__ rotations,  // [EC,3]
    float* __restrict__ out,              // [N,4]
    float* __restrict__ pen,              // scalar (pre-initialized with bbox term)
    int n)
{
    __shared__ NerfParam sp[EC_N];
    __shared__ float s_pen[4];

    const int tid = threadIdx.x;

    // ---- per-block nerflet parameter setup (redundant across blocks, tiny) ----
    if (tid < EC_N) {
        const int e = tid;
        float c = fabsf(constants[e]);
        float r0 = fabsf(radii[e * 3 + 0]) + 0.005f;
        float r1 = fabsf(radii[e * 3 + 1]) + 0.005f;
        float r2 = fabsf(radii[e * 3 + 2]) + 0.005f;
        float d0 = 1.f / (r0 + 1e-8f);
        float d1 = 1.f / (r1 + 1e-8f);
        float d2 = 1.f / (r2 + 1e-8f);
        float ax = rotations[e * 3 + 0];
        float ay = rotations[e * 3 + 1];
        float az = rotations[e * 3 + 2];
        float sx, cx, sy, cy, sz, cz;
        sincosf(ax, &sx, &cx);
        sincosf(ay, &sy, &cy);
        sincosf(az, &sz, &cz);
        float R00 = cz * cy;
        float R01 = cz * sy * sx - sz * cx;
        float R02 = cz * sy * cx + sz * sx;
        float R10 = sz * cy;
        float R11 = sz * sy * sx + cz * cx;
        float R12 = sz * sy * cx - cz * sx;
        float R20 = -sy;
        float R21 = cy * sx;
        float R22 = cy * cx;
        // inv_cov = R diag(d) R^T, scaled by -0.5*log2(e)
        const float k = NEG_HALF_LOG2E;
        float c00 = (R00 * R00 * d0 + R01 * R01 * d1 + R02 * R02 * d2) * k;
        float c11 = (R10 * R10 * d0 + R11 * R11 * d1 + R12 * R12 * d2) * k;
        float c22 = (R20 * R20 * d0 + R21 * R21 * d1 + R22 * R22 * d2) * k;
        float c01 = (R00 * R10 * d0 + R01 * R11 * d1 + R02 * R12 * d2) * k;
        float c02 = (R00 * R20 * d0 + R01 * R21 * d1 + R02 * R22 * d2) * k;
        float c12 = (R10 * R20 * d0 + R11 * R21 * d1 + R12 * R22 * d2) * k;
        NerfParam p;
        p.c00 = c00; p.c11 = c11; p.c22 = c22;
        p.c01_2 = 2.f * c01; p.c02_2 = 2.f * c02; p.c12_2 = 2.f * c12;
        p.cx = centers[e * 3 + 0];
        p.cy = centers[e * 3 + 1];
        p.cz = centers[e * 3 + 2];
        p.cc = c;
        p.pad0 = 0.f; p.pad1 = 0.f;
        sp[e] = p;
    }
    __syncthreads();

    // two points per thread: i0 = blockIdx*512 + tid, i1 = i0 + 256
    const int i0 = blockIdx.x * 512 + tid;
    const int i1 = i0 + 256;
    const bool ok0 = i0 < n;
    const bool ok1 = i1 < n;
    const int j0 = ok0 ? i0 : 0;   // safe clamped indices for loads
    const int j1 = ok1 ? i1 : 0;

    const float px0 = wsp[j0 * 3 + 0], py0 = wsp[j0 * 3 + 1], pz0 = wsp[j0 * 3 + 2];
    const float px1 = wsp[j1 * 3 + 0], py1 = wsp[j1 * 3 + 1], pz1 = wsp[j1 * 3 + 2];
    const float dl0 = dists[j0] * NEG_LOG2E;   // alpha = 1 - exp2(relu(w)*dl)
    const float dl1 = dists[j1] * NEG_LOG2E;

    const v4f* pa0 = (const v4f*)act + j0;
    const v4f* pa1 = (const v4f*)act + j1;

    float S0 = 0.f, u0 = 0.f, u1 = 0.f, u2 = 0.f, u3 = 0.f, pen0 = 0.f;
    float S1 = 0.f, w0 = 0.f, w1 = 0.f, w2 = 0.f, w3 = 0.f, pen1 = 0.f;

    #pragma unroll 8
    for (int e = 0; e < EC_N; ++e) {
        const NerfParam p = sp[e];

        // issue both streaming loads early
        const v4f a0 = __builtin_nontemporal_load(pa0); pa0 += n;
        const v4f a1 = __builtin_nontemporal_load(pa1); pa1 += n;

        // ---- point 0 ----
        {
            const float x = px0 - p.cx, y = py0 - p.cy, z = pz0 - p.cz;
            float q = x * x * p.c00;
            q = fmaf(y * y, p.c11, q);
            q = fmaf(z * z, p.c22, q);
            q = fmaf(x * y, p.c01_2, q);
            q = fmaf(x * z, p.c02_2, q);
            q = fmaf(y * z, p.c12_2, q);
            const float rbf = fast_exp2(q) * p.cc;
            S0 += rbf;
            pen0 += fmaxf(rbf - 0.01f, 0.f);
            const float s0 = fast_rcp(1.f + fast_exp2(a0.x * NEG_LOG2E));
            const float s1 = fast_rcp(1.f + fast_exp2(a0.y * NEG_LOG2E));
            const float s2 = fast_rcp(1.f + fast_exp2(a0.z * NEG_LOG2E));
            const float al = 1.f - fast_exp2(fmaxf(a0.w, 0.f) * dl0);
            u0 = fmaf(rbf, s0, u0);
            u1 = fmaf(rbf, s1, u1);
            u2 = fmaf(rbf, s2, u2);
            u3 = fmaf(rbf, al, u3);
        }
        // ---- point 1 ----
        {
            const float x = px1 - p.cx, y = py1 - p.cy, z = pz1 - p.cz;
            float q = x * x * p.c00;
            q = fmaf(y * y, p.c11, q);
            q = fmaf(z * z, p.c22, q);
            q = fmaf(x * y, p.c01_2, q);
            q = fmaf(x * z, p.c02_2, q);
            q = fmaf(y * z, p.c12_2, q);
            const float rbf = fast_exp2(q) * p.cc;
            S1 += rbf;
            pen1 += fmaxf(rbf - 0.01f, 0.f);
            const float s0 = fast_rcp(1.f + fast_exp2(a1.x * NEG_LOG2E));
            const float s1 = fast_rcp(1.f + fast_exp2(a1.y * NEG_LOG2E));
            const float s2 = fast_rcp(1.f + fast_exp2(a1.z * NEG_LOG2E));
            const float al = 1.f - fast_exp2(fmaxf(a1.w, 0.f) * dl1);
            w0 = fmaf(rbf, s0, w0);
            w1 = fmaf(rbf, s1, w1);
            w2 = fmaf(rbf, s2, w2);
            w3 = fmaf(rbf, al, w3);
        }
    }

    if (ok0) {
        const float inv = fast_rcp(S0 + 1e-6f);
        v4f o; o.x = u0 * inv; o.y = u1 * inv; o.z = u2 * inv; o.w = u3 * inv;
        __builtin_nontemporal_store(o, (v4f*)out + i0);
    }
    if (ok1) {
        const float inv = fast_rcp(S1 + 1e-6f);
        v4f o; o.x = w0 * inv; o.y = w1 * inv; o.z = w2 * inv; o.w = w3 * inv;
        __builtin_nontemporal_store(o, (v4f*)out + i1);
    }

    // ---- penalty reduction: shuffle within wave, LDS across waves, one atomic/block ----
    float penLocal = (ok0 ? pen0 : 0.f) + (ok1 ? pen1 : 0.f);
    #pragma unroll
    for (int off = 32; off > 0; off >>= 1)
        penLocal += __shfl_down(penLocal, off, 64);
    const int wave = tid >> 6;
    const int lane = tid & 63;
    if (lane == 0) s_pen[wave] = penLocal;
    __syncthreads();
    if (tid == 0) {
        const float t = s_pen[0] + s_pen[1] + s_pen[2] + s_pen[3];
        atomicAdd(pen, t * (0.001f / (float)n));
    }
}

extern "C" void kernel_launch(void* const* d_in, const int* in_sizes, int n_in,
                              void* d_out, int out_size, void* d_ws, size_t ws_size,
                              hipStream_t stream) {
    const float* wsp       = (const float*)d_in[0];
    const float* act       = (const float*)d_in[1];
    const float* dists     = (const float*)d_in[2];
    const float* constants = (const float*)d_in[3];
    const float* centers   = (const float*)d_in[4];
    const float* radii     = (const float*)d_in[5];
    const float* rotations = (const float*)d_in[6];

    const int n = in_sizes[0] / 3;           // world_space_points is [N,3]
    float* out = (float*)d_out;              // [N,4] flat
    float* pen = out + (size_t)n * 4;        // scalar penalty at the end

    init_penalty_kernel<<<1, 64, 0, stream>>>(centers, pen);

    const int blocks = (n + 511) / 512;      // 2 points per thread
    rbf_main_kernel<<<blocks, 256, 0, stream>>>(
        wsp, act, dists, constants, centers, radii, rotations, out, pen, n);
}

// Round 3
// 356.644 us; speedup vs baseline: 1.0367x; 1.0109x over previous
//
#include <hip/hip_runtime.h>
#include <math.h>

#define EC_N 64
// exp(-0.5*q) == exp2(q * -0.5*log2(e)); fold the scale into the coefficients
#define NEG_HALF_LOG2E (-0.72134752044448170368f)
#define NEG_LOG2E      (-1.44269504088896340736f)

typedef float v4f __attribute__((ext_vector_type(4)));

struct __align__(16) NerfParam {
    // q' = c00*x*x + c11*y*y + c22*z*z + c01_2*x*y + c02_2*x*z + c12_2*y*z
    // coefficients pre-scaled by -0.5*log2(e) so rbf = exp2(q') * cc
    float c00, c11, c22, c01_2;
    float c02_2, c12_2, cx, cy;
    float cz, cc, pad0, pad1;
};

__device__ __forceinline__ float fast_exp2(float x) { return __builtin_amdgcn_exp2f(x); }
__device__ __forceinline__ float fast_rcp(float x)  { return __builtin_amdgcn_rcpf(x); }
__device__ __forceinline__ v4f nt_load(const v4f* p) { return __builtin_nontemporal_load(p); }

__global__ void init_penalty_kernel(const float* __restrict__ centers,
                                    float* __restrict__ pen_out) {
    int e = threadIdx.x;
    float p = 0.f;
    if (e < EC_N) {
        const float bmax[3] = {0.6f, 0.6f, 0.6f};
        const float bmin[3] = {-0.6f, -0.6f, -0.35f};
        #pragma unroll
        for (int k = 0; k < 3; ++k) {
            float cv = centers[e * 3 + k];
            p += fmaxf(cv - bmax[k], 0.f) + fmaxf(bmin[k] - cv, 0.f);
        }
    }
    #pragma unroll
    for (int off = 32; off > 0; off >>= 1)
        p += __shfl_down(p, off, 64);
    if (threadIdx.x == 0) *pen_out = p;   // main kernel atomicAdds on top
}

__global__ __launch_bounds__(256, 4) void rbf_main_kernel(
    const float* __restrict__ wsp,        // [N,3]
    const float* __restrict__ act,        // [EC,N,4]
    const float* __restrict__ dists,      // [N,1]
    const float* __restrict__ constants,  // [EC,1]
    const float* __restrict__ centers,    // [EC,3]
    const float* __restrict__ radii,      // [EC,3]
    const float* __restrict__ rotations,  // [EC,3]
    float* __restrict__ out,              // [N,4]
    float* __restrict__ pen,              // scalar (pre-initialized with bbox term)
    int n)
{
    __shared__ NerfParam sp[EC_N];
    __shared__ float s_pen[4];

    const int tid = threadIdx.x;

    // ---- per-block nerflet parameter setup (redundant across blocks, tiny) ----
    if (tid < EC_N) {
        const int e = tid;
        float c = fabsf(constants[e]);
        float r0 = fabsf(radii[e * 3 + 0]) + 0.005f;
        float r1 = fabsf(radii[e * 3 + 1]) + 0.005f;
        float r2 = fabsf(radii[e * 3 + 2]) + 0.005f;
        float d0 = 1.f / (r0 + 1e-8f);
        float d1 = 1.f / (r1 + 1e-8f);
        float d2 = 1.f / (r2 + 1e-8f);
        float ax = rotations[e * 3 + 0];
        float ay = rotations[e * 3 + 1];
        float az = rotations[e * 3 + 2];
        float sx, cx, sy, cy, sz, cz;
        sincosf(ax, &sx, &cx);
        sincosf(ay, &sy, &cy);
        sincosf(az, &sz, &cz);
        float R00 = cz * cy;
        float R01 = cz * sy * sx - sz * cx;
        float R02 = cz * sy * cx + sz * sx;
        float R10 = sz * cy;
        float R11 = sz * sy * sx + cz * cx;
        float R12 = sz * sy * cx - cz * sx;
        float R20 = -sy;
        float R21 = cy * sx;
        float R22 = cy * cx;
        const float k = NEG_HALF_LOG2E;
        float c00 = (R00 * R00 * d0 + R01 * R01 * d1 + R02 * R02 * d2) * k;
        float c11 = (R10 * R10 * d0 + R11 * R11 * d1 + R12 * R12 * d2) * k;
        float c22 = (R20 * R20 * d0 + R21 * R21 * d1 + R22 * R22 * d2) * k;
        float c01 = (R00 * R10 * d0 + R01 * R11 * d1 + R02 * R12 * d2) * k;
        float c02 = (R00 * R20 * d0 + R01 * R21 * d1 + R02 * R22 * d2) * k;
        float c12 = (R10 * R20 * d0 + R11 * R21 * d1 + R12 * R22 * d2) * k;
        NerfParam p;
        p.c00 = c00; p.c11 = c11; p.c22 = c22;
        p.c01_2 = 2.f * c01; p.c02_2 = 2.f * c02; p.c12_2 = 2.f * c12;
        p.cx = centers[e * 3 + 0];
        p.cy = centers[e * 3 + 1];
        p.cz = centers[e * 3 + 2];
        p.cc = c;
        p.pad0 = 0.f; p.pad1 = 0.f;
        sp[e] = p;
    }
    __syncthreads();

    const int i = blockIdx.x * 256 + tid;   // one point per thread
    const bool ok = i < n;
    const int j = ok ? i : 0;

    const float px = wsp[j * 3 + 0];
    const float py = wsp[j * 3 + 1];
    const float pz = wsp[j * 3 + 2];
    const float dl = dists[j] * NEG_LOG2E;  // alpha = 1 - exp2(relu(w)*dl)

    // two independent e-streams (e in [0,32) and [32,64)), prefetch distance 2 each
    const v4f* plo = (const v4f*)act + j;                      // e = 0
    const v4f* phi = (const v4f*)act + ((size_t)32 * n + j);   // e = 32

    v4f A0 = nt_load(plo); plo += n;   // e=0
    v4f B0 = nt_load(phi); phi += n;   // e=32
    v4f A1 = nt_load(plo); plo += n;   // e=1   (plo now -> e=2)
    v4f B1 = nt_load(phi); phi += n;   // e=33  (phi now -> e=34)

    float S = 0.f, v0 = 0.f, v1 = 0.f, v2 = 0.f, v3 = 0.f, penL = 0.f;

    #pragma unroll 2
    for (int e = 0; e < 32; ++e) {
        const v4f aLo = A0; A0 = A1;
        const v4f aHi = B0; B0 = B1;
        if (e < 30) {                       // uniform branch: prefetch e+2 / e+34
            A1 = nt_load(plo); plo += n;
            B1 = nt_load(phi); phi += n;
        }

        // ---- stream lo: nerflet e ----
        {
            const NerfParam p = sp[e];
            const float x = px - p.cx, y = py - p.cy, z = pz - p.cz;
            float q = x * x * p.c00;
            q = fmaf(y * y, p.c11, q);
            q = fmaf(z * z, p.c22, q);
            q = fmaf(x * y, p.c01_2, q);
            q = fmaf(x * z, p.c02_2, q);
            q = fmaf(y * z, p.c12_2, q);
            const float rbf = fast_exp2(q) * p.cc;
            S += rbf;
            penL += fmaxf(rbf - 0.01f, 0.f);
            const float s0 = fast_rcp(1.f + fast_exp2(aLo.x * NEG_LOG2E));
            const float s1 = fast_rcp(1.f + fast_exp2(aLo.y * NEG_LOG2E));
            const float s2 = fast_rcp(1.f + fast_exp2(aLo.z * NEG_LOG2E));
            const float al = 1.f - fast_exp2(fmaxf(aLo.w, 0.f) * dl);
            v0 = fmaf(rbf, s0, v0);
            v1 = fmaf(rbf, s1, v1);
            v2 = fmaf(rbf, s2, v2);
            v3 = fmaf(rbf, al, v3);
        }
        // ---- stream hi: nerflet e+32 ----
        {
            const NerfParam p = sp[e + 32];
            const float x = px - p.cx, y = py - p.cy, z = pz - p.cz;
            float q = x * x * p.c00;
            q = fmaf(y * y, p.c11, q);
            q = fmaf(z * z, p.c22, q);
            q = fmaf(x * y, p.c01_2, q);
            q = fmaf(x * z, p.c02_2, q);
            q = fmaf(y * z, p.c12_2, q);
            const float rbf = fast_exp2(q) * p.cc;
            S += rbf;
            penL += fmaxf(rbf - 0.01f, 0.f);
            const float s0 = fast_rcp(1.f + fast_exp2(aHi.x * NEG_LOG2E));
            const float s1 = fast_rcp(1.f + fast_exp2(aHi.y * NEG_LOG2E));
            const float s2 = fast_rcp(1.f + fast_exp2(aHi.z * NEG_LOG2E));
            const float al = 1.f - fast_exp2(fmaxf(aHi.w, 0.f) * dl);
            v0 = fmaf(rbf, s0, v0);
            v1 = fmaf(rbf, s1, v1);
            v2 = fmaf(rbf, s2, v2);
            v3 = fmaf(rbf, al, v3);
        }
    }

    if (ok) {
        const float inv = fast_rcp(S + 1e-6f);
        v4f o; o.x = v0 * inv; o.y = v1 * inv; o.z = v2 * inv; o.w = v3 * inv;
        __builtin_nontemporal_store(o, (v4f*)out + i);
    }

    // ---- penalty reduction: shuffle within wave, LDS across waves, one atomic/block ----
    float penLocal = ok ? penL : 0.f;
    #pragma unroll
    for (int off = 32; off > 0; off >>= 1)
        penLocal += __shfl_down(penLocal, off, 64);
    const int wave = tid >> 6;
    const int lane = tid & 63;
    if (lane == 0) s_pen[wave] = penLocal;
    __syncthreads();
    if (tid == 0) {
        const float t = s_pen[0] + s_pen[1] + s_pen[2] + s_pen[3];
        atomicAdd(pen, t * (0.001f / (float)n));
    }
}

extern "C" void kernel_launch(void* const* d_in, const int* in_sizes, int n_in,
                              void* d_out, int out_size, void* d_ws, size_t ws_size,
                              hipStream_t stream) {
    const float* wsp       = (const float*)d_in[0];
    const float* act       = (const float*)d_in[1];
    const float* dists     = (const float*)d_in[2];
    const float* constants = (const float*)d_in[3];
    const float* centers   = (const float*)d_in[4];
    const float* radii     = (const float*)d_in[5];
    const float* rotations = (const float*)d_in[6];

    const int n = in_sizes[0] / 3;           // world_space_points is [N,3]
    float* out = (float*)d_out;              // [N,4] flat
    float* pen = out + (size_t)n * 4;        // scalar penalty at the end

    init_penalty_kernel<<<1, 64, 0, stream>>>(centers, pen);

    const int blocks = (n + 255) / 256;      // 1 point per thread, 1024 blocks
    rbf_main_kernel<<<blocks, 256, 0, stream>>>(
        wsp, act, dists, constants, centers, radii, rotations, out, pen, n);
}